// Round 2
// baseline (174.738 us; speedup 1.0000x reference)
//
#include <hip/hip_runtime.h>
#include <math.h>

#define PAD_IDX 0
#define BIGV 10000.0f
constexpr int B_ = 1024, S_ = 128, V_ = 200, E_ = 512, H_ = 512, T_ = 24;

// ---------------------------------------------------------------------------
// Kernel A: em_table[v][t] = relu( relu(emb[v] @ w1^T + b1) @ w2^T + b2 )
//           with BIG baked into em_table[0][PAD] (token 0 == PAD).
// One block per vocab row v. x and h staged in LDS.
// ---------------------------------------------------------------------------
__global__ __launch_bounds__(256) void emis_table_kernel(
    const float* __restrict__ emb, const float* __restrict__ w1,
    const float* __restrict__ b1, const float* __restrict__ w2,
    const float* __restrict__ b2, float* __restrict__ em_table)
{
    __shared__ float xs[E_];
    __shared__ float hs[H_];
    const int v = blockIdx.x;
    const int t = threadIdx.x;

    xs[t]       = emb[(size_t)v * E_ + t];
    xs[t + 256] = emb[(size_t)v * E_ + t + 256];
    __syncthreads();

    const float4* xv = (const float4*)xs;
    // each thread computes h[t] and h[t+256]
    #pragma unroll
    for (int rr = 0; rr < 2; rr++) {
        const int row = t + rr * 256;
        const float4* wv = (const float4*)(w1 + (size_t)row * H_);
        float a0 = 0.f, a1 = 0.f, a2 = 0.f, a3 = 0.f;
        #pragma unroll 4
        for (int k = 0; k < E_ / 4; k++) {
            float4 w = wv[k];
            float4 x = xv[k];
            a0 = fmaf(w.x, x.x, a0);
            a1 = fmaf(w.y, x.y, a1);
            a2 = fmaf(w.z, x.z, a2);
            a3 = fmaf(w.w, x.w, a3);
        }
        hs[row] = fmaxf((a0 + a1) + (a2 + a3) + b1[row], 0.f);
    }
    __syncthreads();

    // projection to T=24 outputs: 4 waves x 6 outputs, split-512 dot + reduce
    const int wave = t >> 6, lane = t & 63;
    for (int jj = 0; jj < 6; jj++) {
        const int j = wave * 6 + jj;
        float part = 0.f;
        #pragma unroll
        for (int k = lane; k < H_; k += 64)
            part = fmaf(hs[k], w2[(size_t)j * H_ + k], part);
        #pragma unroll
        for (int off = 32; off; off >>= 1)
            part += __shfl_xor(part, off, 64);
        if (lane == 0) {
            float val = fmaxf(part + b2[j], 0.f);
            if (v == 0 && j == PAD_IDX) val += BIGV;  // pad boost baked in
            em_table[v * T_ + j] = val;
        }
    }
}

// ---------------------------------------------------------------------------
// Kernel B: per-batch CRF forward algorithm + gold path score.
// 256 threads = 8 batches/block, 32 lanes per batch (j = state, j<24 active).
// alpha kept lane-per-state in registers; exchange via width-32 shuffles.
// E = exp(transitions) hoisted: LSE_i(a_i + tr_ij) = m + log(sum p_i * E_ij).
// ---------------------------------------------------------------------------
__global__ __launch_bounds__(256) void crf_kernel(
    const int* __restrict__ seq, const int* __restrict__ labels,
    const float* __restrict__ start_t, const float* __restrict__ end_t,
    const float* __restrict__ trans, const float* __restrict__ em_table,
    float* __restrict__ llh)
{
    __shared__ float tbl[V_ * T_];
    const int tid = threadIdx.x;
    for (int i = tid; i < V_ * T_; i += 256) tbl[i] = em_table[i];
    __syncthreads();

    const int grp = tid >> 5;
    const int j   = tid & 31;
    const int b   = blockIdx.x * 8 + grp;
    const int jj  = (j < T_) ? j : 0;
    const bool act = (j < T_);

    float Ecol[T_];
    #pragma unroll
    for (int i = 0; i < T_; i++)
        Ecol[i] = act ? __expf(trans[i * T_ + jj]) : 0.f;

    const int* srow = seq + (size_t)b * S_;
    const int* lrow = labels + (size_t)b * S_;

    const int tok0 = srow[0];
    float alpha = act ? (start_t[jj] + tbl[tok0 * T_ + jj]) : -INFINITY;

    for (int s = 1; s < S_; s++) {
        const int tok = srow[s];
        const float emit = tbl[tok * T_ + jj];
        float m = alpha;
        #pragma unroll
        for (int off = 16; off; off >>= 1)
            m = fmaxf(m, __shfl_xor(m, off, 32));
        const float p = __expf(alpha - m);   // exactly 0 for inactive lanes
        float s0 = 0.f, s1 = 0.f, s2 = 0.f, s3 = 0.f;
        #pragma unroll
        for (int i = 0; i < T_; i += 4) {
            s0 = fmaf(__shfl(p, i,     32), Ecol[i],     s0);
            s1 = fmaf(__shfl(p, i + 1, 32), Ecol[i + 1], s1);
            s2 = fmaf(__shfl(p, i + 2, 32), Ecol[i + 2], s2);
            s3 = fmaf(__shfl(p, i + 3, 32), Ecol[i + 3], s3);
        }
        const float ssum = (s0 + s1) + (s2 + s3);
        alpha = act ? (m + __logf(ssum) + emit) : -INFINITY;
    }

    // denominator: logsumexp(alpha + end_trans)
    float vterm = act ? (alpha + end_t[jj]) : -INFINITY;
    float m = vterm;
    #pragma unroll
    for (int off = 16; off; off >>= 1)
        m = fmaxf(m, __shfl_xor(m, off, 32));
    float p = __expf(vterm - m);
    #pragma unroll
    for (int off = 16; off; off >>= 1)
        p += __shfl_xor(p, off, 32);
    const float denom = m + __logf(p);

    // numerator (gold path): lane j handles steps j, j+32, j+64, j+96
    float part = 0.f;
    #pragma unroll
    for (int r = 0; r < 4; r++) {
        const int s = j + r * 32;
        const int ls = lrow[s];
        part += tbl[srow[s] * T_ + ls];
        if (s < S_ - 1) part += trans[ls * T_ + lrow[s + 1]];
        if (s == 0)     part += start_t[ls];
        if (s == S_ - 1) part += end_t[ls];
    }
    #pragma unroll
    for (int off = 16; off; off >>= 1)
        part += __shfl_xor(part, off, 32);

    if (j == 0) llh[b] = part - denom;
}

// ---------------------------------------------------------------------------
// Kernel C: out = -mean(llh) over 1024 batches.
// ---------------------------------------------------------------------------
__global__ __launch_bounds__(1024) void reduce_kernel(
    const float* __restrict__ llh, float* __restrict__ out)
{
    __shared__ float wsum[16];
    const int tid = threadIdx.x;
    float v = llh[tid];
    #pragma unroll
    for (int off = 32; off; off >>= 1)
        v += __shfl_xor(v, off, 64);
    if ((tid & 63) == 0) wsum[tid >> 6] = v;
    __syncthreads();
    if (tid < 64) {
        float x = (tid < 16) ? wsum[tid] : 0.f;
        #pragma unroll
        for (int off = 32; off; off >>= 1)
            x += __shfl_xor(x, off, 64);
        if (tid == 0) out[0] = -(x / (float)B_);
    }
}

// ---------------------------------------------------------------------------
extern "C" void kernel_launch(void* const* d_in, const int* in_sizes, int n_in,
                              void* d_out, int out_size, void* d_ws, size_t ws_size,
                              hipStream_t stream) {
    const int*   seq    = (const int*)d_in[0];
    const int*   labels = (const int*)d_in[1];
    // d_in[2] true_lengths: unused by the reference forward
    const float* emb    = (const float*)d_in[3];
    const float* w1     = (const float*)d_in[4];
    const float* b1     = (const float*)d_in[5];
    const float* w2     = (const float*)d_in[6];
    const float* b2     = (const float*)d_in[7];
    const float* start_t = (const float*)d_in[8];
    const float* end_t   = (const float*)d_in[9];
    const float* trans   = (const float*)d_in[10];

    float* em_table = (float*)d_ws;                 // V*T = 4800 floats
    float* llh      = em_table + V_ * T_;           // B = 1024 floats
    float* out      = (float*)d_out;

    emis_table_kernel<<<V_, 256, 0, stream>>>(emb, w1, b1, w2, b2, em_table);
    crf_kernel<<<B_ / 8, 256, 0, stream>>>(seq, labels, start_t, end_t, trans,
                                           em_table, llh);
    reduce_kernel<<<1, 1024, 0, stream>>>(llh, out);
}

// Round 3
// 152.740 us; speedup vs baseline: 1.1440x; 1.1440x over previous
//
#include <hip/hip_runtime.h>
#include <math.h>

#define PAD_IDX 0
#define BIGV 10000.0f
constexpr int B_ = 1024, S_ = 128, V_ = 200, E_ = 512, H_ = 512, T_ = 24;

// ---------------------------------------------------------------------------
// Kernel A: per-token emission table + exp-normalized table + row max.
//   em_table[v][t] = relu( relu(emb[v]@w1^T + b1) @ w2^T + b2 )  (+BIG at [0][0])
//   emax[v]       = max_t em_table[v][t]
//   w_table[v][t] = exp(em_table[v][t] - emax[v])
// One block per v. Phase 1: split-K over 64 lanes (coalesced w1 reads),
// 2-row unroll, shfl reduce. Phase 2: 4 waves x 6 outputs. Phase 3: normalize.
// ---------------------------------------------------------------------------
__global__ __launch_bounds__(256) void emis_table_kernel(
    const float* __restrict__ emb, const float* __restrict__ w1,
    const float* __restrict__ b1, const float* __restrict__ w2,
    const float* __restrict__ b2, float* __restrict__ em_table,
    float* __restrict__ w_table, float* __restrict__ emax_arr)
{
    __shared__ float hs[H_];
    __shared__ float em_row[32];
    const int v = blockIdx.x;
    const int t = threadIdx.x;
    const int wave = t >> 6, lane = t & 63;

    // x fragment in registers: lane holds emb[v][8*lane .. 8*lane+7]
    const float4 xa = *(const float4*)&emb[(size_t)v * E_ + lane * 8];
    const float4 xb = *(const float4*)&emb[(size_t)v * E_ + lane * 8 + 4];

    // phase 1: h rows, 128 per wave, 2 at a time
    for (int r0 = wave * 128; r0 < wave * 128 + 128; r0 += 2) {
        const float4 wa0 = *(const float4*)&w1[(size_t)r0 * E_ + lane * 8];
        const float4 wb0 = *(const float4*)&w1[(size_t)r0 * E_ + lane * 8 + 4];
        const float4 wa1 = *(const float4*)&w1[(size_t)(r0 + 1) * E_ + lane * 8];
        const float4 wb1 = *(const float4*)&w1[(size_t)(r0 + 1) * E_ + lane * 8 + 4];
        float p0 = wa0.x * xa.x;
        p0 = fmaf(wa0.y, xa.y, p0); p0 = fmaf(wa0.z, xa.z, p0);
        p0 = fmaf(wa0.w, xa.w, p0); p0 = fmaf(wb0.x, xb.x, p0);
        p0 = fmaf(wb0.y, xb.y, p0); p0 = fmaf(wb0.z, xb.z, p0);
        p0 = fmaf(wb0.w, xb.w, p0);
        float p1 = wa1.x * xa.x;
        p1 = fmaf(wa1.y, xa.y, p1); p1 = fmaf(wa1.z, xa.z, p1);
        p1 = fmaf(wa1.w, xa.w, p1); p1 = fmaf(wb1.x, xb.x, p1);
        p1 = fmaf(wb1.y, xb.y, p1); p1 = fmaf(wb1.z, xb.z, p1);
        p1 = fmaf(wb1.w, xb.w, p1);
        #pragma unroll
        for (int off = 32; off; off >>= 1) {
            p0 += __shfl_xor(p0, off, 64);
            p1 += __shfl_xor(p1, off, 64);
        }
        if (lane == 0) {
            hs[r0]     = fmaxf(p0 + b1[r0], 0.f);
            hs[r0 + 1] = fmaxf(p1 + b1[r0 + 1], 0.f);
        }
    }
    __syncthreads();

    // phase 2: 24 outputs, 6 per wave
    for (int jj2 = 0; jj2 < 6; ++jj2) {
        const int jo = wave * 6 + jj2;
        float part = 0.f;
        #pragma unroll
        for (int k = lane; k < H_; k += 64)
            part = fmaf(hs[k], w2[(size_t)jo * H_ + k], part);
        #pragma unroll
        for (int off = 32; off; off >>= 1)
            part += __shfl_xor(part, off, 64);
        if (lane == 0) {
            float val = fmaxf(part + b2[jo], 0.f);
            if (v == 0 && jo == PAD_IDX) val += BIGV;  // pad boost baked in
            em_row[jo] = val;
        }
    }
    __syncthreads();

    // phase 3: row max, exp-normalized table
    if (t < 32) {
        float x = (t < T_) ? em_row[t] : -INFINITY;
        float mx = x;
        #pragma unroll
        for (int off = 16; off; off >>= 1)
            mx = fmaxf(mx, __shfl_xor(mx, off, 32));
        if (t < T_) {
            em_table[v * T_ + t] = x;
            w_table[v * T_ + t]  = __expf(x - mx);
        }
        if (t == 0) emax_arr[v] = mx;
    }
}

// ---------------------------------------------------------------------------
// Kernel B: CRF forward in probability domain.
//   q'_j = (sum_i q_i * E_ij) * w_tok[j],  E = exp(trans), w from kernel A.
//   Renormalize (max, rcp, log) only every 16 steps.  Sum of emax offsets is
//   chain-independent and folded into the gold-score reduction.
// 256 threads = 8 batches/block, 32 lanes/batch. Broadcasts via ds_swizzle.
// ---------------------------------------------------------------------------
#define ACC4(base)                                                              \
    s0 = fmaf(__uint_as_float(__builtin_amdgcn_ds_swizzle(qi, (base) << 5)),     \
              Ecol[(base)], s0);                                                \
    s1 = fmaf(__uint_as_float(__builtin_amdgcn_ds_swizzle(qi, ((base)+1) << 5)), \
              Ecol[(base)+1], s1);                                              \
    s2 = fmaf(__uint_as_float(__builtin_amdgcn_ds_swizzle(qi, ((base)+2) << 5)), \
              Ecol[(base)+2], s2);                                              \
    s3 = fmaf(__uint_as_float(__builtin_amdgcn_ds_swizzle(qi, ((base)+3) << 5)), \
              Ecol[(base)+3], s3);

__global__ __launch_bounds__(256) void crf_kernel(
    const int* __restrict__ seq, const int* __restrict__ labels,
    const float* __restrict__ start_t, const float* __restrict__ end_t,
    const float* __restrict__ trans, const float* __restrict__ em_table,
    const float* __restrict__ w_table, const float* __restrict__ emax_arr,
    float* __restrict__ llh)
{
    __shared__ float em_s[V_ * T_];
    __shared__ float w_s[V_ * T_];
    __shared__ float emax_s[V_];
    __shared__ int   tok_s[8 * S_];
    const int tid = threadIdx.x;
    for (int i = tid; i < V_ * T_; i += 256) { em_s[i] = em_table[i]; w_s[i] = w_table[i]; }
    for (int i = tid; i < V_; i += 256) emax_s[i] = emax_arr[i];
    {
        const int base = blockIdx.x * 8 * S_;
        #pragma unroll
        for (int i = 0; i < 4; ++i)
            tok_s[tid + i * 256] = seq[base + tid + i * 256];
    }
    __syncthreads();

    const int grp = tid >> 5, j = tid & 31;
    const int b = blockIdx.x * 8 + grp;
    const int jj = (j < T_) ? j : 0;
    const bool act = (j < T_);
    const int* __restrict__ lrow = labels + (size_t)b * S_;
    const int* __restrict__ tks  = tok_s + grp * S_;

    float Ecol[T_];
    #pragma unroll
    for (int i = 0; i < T_; ++i)
        Ecol[i] = __expf(trans[i * T_ + jj]);

    // init: alpha0 in log domain, one exp into prob domain
    const int tok0 = tks[0];
    const float a0 = start_t[jj] + em_s[tok0 * T_ + jj];
    float m0 = a0;
    #pragma unroll
    for (int off = 16; off; off >>= 1)
        m0 = fmaxf(m0, __shfl_xor(m0, off, 32));
    float q = __expf(a0 - m0);   // inactive lanes mirror state 0: harmless
    float logacc = m0;

    // software pipeline: wv = w row for step s; tokB = token for step s+1
    float wv; int tokB;
    { const int tA = tks[1]; wv = w_s[tA * T_ + jj]; tokB = tks[2]; }

    for (int s = 1; s < S_; ++s) {
        const float wn = w_s[tokB * T_ + jj];            // emit weights, step s+1
        const int tokC = tks[(s + 2 < S_) ? s + 2 : S_ - 1];
        const unsigned qi = __float_as_uint(q);
        float s0 = 0.f, s1 = 0.f, s2 = 0.f, s3 = 0.f;
        ACC4(0) ACC4(4) ACC4(8) ACC4(12) ACC4(16) ACC4(20)
        q = ((s0 + s1) + (s2 + s3)) * wv;
        wv = wn; tokB = tokC;
        if ((s & 15) == 0) {                              // renorm every 16 steps
            float m = q;
            #pragma unroll
            for (int off = 16; off; off >>= 1)
                m = fmaxf(m, __shfl_xor(m, off, 32));
            q *= (1.0f / m);
            logacc += __logf(m);
        }
    }

    // denominator tail: log sum q_j * exp(end_j)
    float fin = act ? q * __expf(end_t[jj]) : 0.f;
    #pragma unroll
    for (int off = 16; off; off >>= 1)
        fin += __shfl_xor(fin, off, 32);
    const float denom_part = logacc + __logf(fin);  // missing Sum emax, folded below

    // gold path score minus Sum_{s>=1} emax[tok_s]
    float gp = 0.f;
    #pragma unroll
    for (int r = 0; r < 4; ++r) {
        const int s = j + r * 32;
        const int tk = tks[s];
        const int ls = lrow[s];
        gp += em_s[tk * T_ + ls];
        if (s >= 1) gp -= emax_s[tk];
        if (s < S_ - 1) gp += trans[ls * T_ + lrow[s + 1]];
        if (s == 0) gp += start_t[ls];
        if (s == S_ - 1) gp += end_t[ls];
    }
    #pragma unroll
    for (int off = 16; off; off >>= 1)
        gp += __shfl_xor(gp, off, 32);

    if (j == 0) llh[b] = gp - denom_part;
}

// ---------------------------------------------------------------------------
// Kernel C: out = -mean(llh) over 1024 batches.
// ---------------------------------------------------------------------------
__global__ __launch_bounds__(1024) void reduce_kernel(
    const float* __restrict__ llh, float* __restrict__ out)
{
    __shared__ float wsum[16];
    const int tid = threadIdx.x;
    float v = llh[tid];
    #pragma unroll
    for (int off = 32; off; off >>= 1)
        v += __shfl_xor(v, off, 64);
    if ((tid & 63) == 0) wsum[tid >> 6] = v;
    __syncthreads();
    if (tid < 64) {
        float x = (tid < 16) ? wsum[tid] : 0.f;
        #pragma unroll
        for (int off = 32; off; off >>= 1)
            x += __shfl_xor(x, off, 64);
        if (tid == 0) out[0] = -(x / (float)B_);
    }
}

// ---------------------------------------------------------------------------
extern "C" void kernel_launch(void* const* d_in, const int* in_sizes, int n_in,
                              void* d_out, int out_size, void* d_ws, size_t ws_size,
                              hipStream_t stream) {
    const int*   seq     = (const int*)d_in[0];
    const int*   labels  = (const int*)d_in[1];
    // d_in[2] true_lengths: unused by the reference forward
    const float* emb     = (const float*)d_in[3];
    const float* w1      = (const float*)d_in[4];
    const float* b1      = (const float*)d_in[5];
    const float* w2      = (const float*)d_in[6];
    const float* b2      = (const float*)d_in[7];
    const float* start_t = (const float*)d_in[8];
    const float* end_t   = (const float*)d_in[9];
    const float* trans   = (const float*)d_in[10];

    float* em_table = (float*)d_ws;                   // V*T
    float* w_table  = em_table + V_ * T_;             // V*T
    float* emax_arr = w_table + V_ * T_;              // V
    float* llh      = emax_arr + V_;                  // B
    float* out      = (float*)d_out;

    emis_table_kernel<<<V_, 256, 0, stream>>>(emb, w1, b1, w2, b2,
                                              em_table, w_table, emax_arr);
    crf_kernel<<<B_ / 8, 256, 0, stream>>>(seq, labels, start_t, end_t, trans,
                                           em_table, w_table, emax_arr, llh);
    reduce_kernel<<<1, 1024, 0, stream>>>(llh, out);
}

// Round 4
// 142.337 us; speedup vs baseline: 1.2276x; 1.0731x over previous
//
#include <hip/hip_runtime.h>
#include <math.h>

#define PAD_IDX 0
#define BIGV 10000.0f
constexpr int B_ = 1024, S_ = 128, V_ = 200, E_ = 512, H_ = 512, T_ = 24;

// ---------------------------------------------------------------------------
// Kernel A: per-token emission table + exp-normalized table + row max.
//   em_table[v][t] = relu( relu(emb[v]@w1^T + b1) @ w2^T + b2 )  (+BIG at [0][0])
//   emax[v]       = max_t em_table[v][t]
//   w_table[v][t] = exp(em_table[v][t] - emax[v])
// One block per v. Phase 1: thread-per-output (t computes h[t], h[t+256]) —
// no shuffles, deep ILP, x broadcast from LDS. Latency-bound fix vs R3:
// the wave-per-row shfl-reduce put 6 dependent shuffles + load latency in
// series 64x with 0.78 waves/SIMD; this version has 8 loads in flight and
// 8 independent FMA chains per thread.
// Also zeroes out[0] (block 0) for crf's fused atomic mean-reduction.
// ---------------------------------------------------------------------------
__global__ __launch_bounds__(256) void emis_table_kernel(
    const float* __restrict__ emb, const float* __restrict__ w1,
    const float* __restrict__ b1, const float* __restrict__ w2,
    const float* __restrict__ b2, float* __restrict__ em_table,
    float* __restrict__ w_table, float* __restrict__ emax_arr,
    float* __restrict__ out)
{
    __shared__ float xs[E_];
    __shared__ float hs[H_];
    __shared__ float em_row[32];
    const int v = blockIdx.x;
    const int t = threadIdx.x;

    if (v == 0 && t == 0) out[0] = 0.f;   // accumulator for crf atomics

    xs[t]       = emb[(size_t)v * E_ + t];
    xs[t + 256] = emb[(size_t)v * E_ + t + 256];
    __syncthreads();

    // phase 1: h[t] and h[t+256], fused dual 512-dot, unrolled
    {
        const float4* __restrict__ xv  = (const float4*)xs;
        const float4* __restrict__ wv0 = (const float4*)(w1 + (size_t)t * E_);
        const float4* __restrict__ wv1 = (const float4*)(w1 + (size_t)(t + 256) * E_);
        float a0 = 0.f, a1 = 0.f, a2 = 0.f, a3 = 0.f;
        float c0 = 0.f, c1 = 0.f, c2 = 0.f, c3 = 0.f;
        #pragma unroll 4
        for (int k = 0; k < E_ / 4; ++k) {
            const float4 x  = xv[k];
            const float4 w0 = wv0[k];
            const float4 w1v = wv1[k];
            a0 = fmaf(w0.x, x.x, a0);  a1 = fmaf(w0.y, x.y, a1);
            a2 = fmaf(w0.z, x.z, a2);  a3 = fmaf(w0.w, x.w, a3);
            c0 = fmaf(w1v.x, x.x, c0); c1 = fmaf(w1v.y, x.y, c1);
            c2 = fmaf(w1v.z, x.z, c2); c3 = fmaf(w1v.w, x.w, c3);
        }
        hs[t]       = fmaxf((a0 + a1) + (a2 + a3) + b1[t], 0.f);
        hs[t + 256] = fmaxf((c0 + c1) + (c2 + c3) + b1[t + 256], 0.f);
    }
    __syncthreads();

    // phase 2: 24 outputs, 6 per wave, split-K over 64 lanes + shfl reduce
    const int wave = t >> 6, lane = t & 63;
    for (int jj2 = 0; jj2 < 6; ++jj2) {
        const int jo = wave * 6 + jj2;
        float part = 0.f;
        #pragma unroll
        for (int k = lane; k < H_; k += 64)
            part = fmaf(hs[k], w2[(size_t)jo * H_ + k], part);
        #pragma unroll
        for (int off = 32; off; off >>= 1)
            part += __shfl_xor(part, off, 64);
        if (lane == 0) {
            float val = fmaxf(part + b2[jo], 0.f);
            if (v == 0 && jo == PAD_IDX) val += BIGV;  // pad boost baked in
            em_row[jo] = val;
        }
    }
    __syncthreads();

    // phase 3: row max, exp-normalized table
    if (t < 32) {
        float x = (t < T_) ? em_row[t] : -INFINITY;
        float mx = x;
        #pragma unroll
        for (int off = 16; off; off >>= 1)
            mx = fmaxf(mx, __shfl_xor(mx, off, 32));
        if (t < T_) {
            em_table[v * T_ + t] = x;
            w_table[v * T_ + t]  = __expf(x - mx);
        }
        if (t == 0) emax_arr[v] = mx;
    }
}

// ---------------------------------------------------------------------------
// Kernel B: CRF forward in probability domain.
//   q'_j = (sum_i q_i * E_ij) * w_tok[j],  E = exp(trans), w from kernel A.
//   Renormalize (max, rcp, log) only every 16 steps.  Sum of emax offsets is
//   chain-independent and folded into the gold-score reduction.
// 256 threads = 8 batches/block, 32 lanes/batch. Broadcasts via ds_swizzle.
// Fused finale: atomicAdd of (denom - gold)/B into out[0] (zeroed by kernel A).
// ---------------------------------------------------------------------------
#define ACC4(base)                                                              \
    s0 = fmaf(__uint_as_float(__builtin_amdgcn_ds_swizzle(qi, (base) << 5)),     \
              Ecol[(base)], s0);                                                \
    s1 = fmaf(__uint_as_float(__builtin_amdgcn_ds_swizzle(qi, ((base)+1) << 5)), \
              Ecol[(base)+1], s1);                                              \
    s2 = fmaf(__uint_as_float(__builtin_amdgcn_ds_swizzle(qi, ((base)+2) << 5)), \
              Ecol[(base)+2], s2);                                              \
    s3 = fmaf(__uint_as_float(__builtin_amdgcn_ds_swizzle(qi, ((base)+3) << 5)), \
              Ecol[(base)+3], s3);

__global__ __launch_bounds__(256) void crf_kernel(
    const int* __restrict__ seq, const int* __restrict__ labels,
    const float* __restrict__ start_t, const float* __restrict__ end_t,
    const float* __restrict__ trans, const float* __restrict__ em_table,
    const float* __restrict__ w_table, const float* __restrict__ emax_arr,
    float* __restrict__ out)
{
    __shared__ float em_s[V_ * T_];
    __shared__ float w_s[V_ * T_];
    __shared__ float emax_s[V_];
    __shared__ int   tok_s[8 * S_];
    const int tid = threadIdx.x;
    for (int i = tid; i < V_ * T_; i += 256) { em_s[i] = em_table[i]; w_s[i] = w_table[i]; }
    for (int i = tid; i < V_; i += 256) emax_s[i] = emax_arr[i];
    {
        const int base = blockIdx.x * 8 * S_;
        #pragma unroll
        for (int i = 0; i < 4; ++i)
            tok_s[tid + i * 256] = seq[base + tid + i * 256];
    }
    __syncthreads();

    const int grp = tid >> 5, j = tid & 31;
    const int b = blockIdx.x * 8 + grp;
    const int jj = (j < T_) ? j : 0;
    const bool act = (j < T_);
    const int* __restrict__ lrow = labels + (size_t)b * S_;
    const int* __restrict__ tks  = tok_s + grp * S_;

    float Ecol[T_];
    #pragma unroll
    for (int i = 0; i < T_; ++i)
        Ecol[i] = __expf(trans[i * T_ + jj]);

    // init: alpha0 in log domain, one exp into prob domain
    const int tok0 = tks[0];
    const float a0 = start_t[jj] + em_s[tok0 * T_ + jj];
    float m0 = a0;
    #pragma unroll
    for (int off = 16; off; off >>= 1)
        m0 = fmaxf(m0, __shfl_xor(m0, off, 32));
    float q = __expf(a0 - m0);   // inactive lanes mirror state 0: harmless
    float logacc = m0;

    // software pipeline: wv = w row for step s; tokB = token for step s+1
    float wv; int tokB;
    { const int tA = tks[1]; wv = w_s[tA * T_ + jj]; tokB = tks[2]; }

    for (int s = 1; s < S_; ++s) {
        const float wn = w_s[tokB * T_ + jj];            // emit weights, step s+1
        const int tokC = tks[(s + 2 < S_) ? s + 2 : S_ - 1];
        const unsigned qi = __float_as_uint(q);
        float s0 = 0.f, s1 = 0.f, s2 = 0.f, s3 = 0.f;
        ACC4(0) ACC4(4) ACC4(8) ACC4(12) ACC4(16) ACC4(20)
        q = ((s0 + s1) + (s2 + s3)) * wv;
        wv = wn; tokB = tokC;
        if ((s & 15) == 0) {                              // renorm every 16 steps
            float m = q;
            #pragma unroll
            for (int off = 16; off; off >>= 1)
                m = fmaxf(m, __shfl_xor(m, off, 32));
            q *= (1.0f / m);
            logacc += __logf(m);
        }
    }

    // denominator tail: log sum q_j * exp(end_j)
    float fin = act ? q * __expf(end_t[jj]) : 0.f;
    #pragma unroll
    for (int off = 16; off; off >>= 1)
        fin += __shfl_xor(fin, off, 32);
    const float denom_part = logacc + __logf(fin);  // missing Sum emax, folded below

    // gold path score minus Sum_{s>=1} emax[tok_s]
    float gp = 0.f;
    #pragma unroll
    for (int r = 0; r < 4; ++r) {
        const int s = j + r * 32;
        const int tk = tks[s];
        const int ls = lrow[s];
        gp += em_s[tk * T_ + ls];
        if (s >= 1) gp -= emax_s[tk];
        if (s < S_ - 1) gp += trans[ls * T_ + lrow[s + 1]];
        if (s == 0) gp += start_t[ls];
        if (s == S_ - 1) gp += end_t[ls];
    }
    #pragma unroll
    for (int off = 16; off; off >>= 1)
        gp += __shfl_xor(gp, off, 32);

    // fused mean: out = mean_b(denom_b - gold_b) = -mean(llh)
    if (j == 0)
        atomicAdd(out, (denom_part - gp) * (1.0f / (float)B_));
}

// ---------------------------------------------------------------------------
extern "C" void kernel_launch(void* const* d_in, const int* in_sizes, int n_in,
                              void* d_out, int out_size, void* d_ws, size_t ws_size,
                              hipStream_t stream) {
    const int*   seq     = (const int*)d_in[0];
    const int*   labels  = (const int*)d_in[1];
    // d_in[2] true_lengths: unused by the reference forward
    const float* emb     = (const float*)d_in[3];
    const float* w1      = (const float*)d_in[4];
    const float* b1      = (const float*)d_in[5];
    const float* w2      = (const float*)d_in[6];
    const float* b2      = (const float*)d_in[7];
    const float* start_t = (const float*)d_in[8];
    const float* end_t   = (const float*)d_in[9];
    const float* trans   = (const float*)d_in[10];

    float* em_table = (float*)d_ws;                   // V*T
    float* w_table  = em_table + V_ * T_;             // V*T
    float* emax_arr = w_table + V_ * T_;              // V
    float* out      = (float*)d_out;

    emis_table_kernel<<<V_, 256, 0, stream>>>(emb, w1, b1, w2, b2,
                                              em_table, w_table, emax_arr, out);
    crf_kernel<<<B_ / 8, 256, 0, stream>>>(seq, labels, start_t, end_t, trans,
                                           em_table, w_table, emax_arr, out);
}

// Round 5
// 127.471 us; speedup vs baseline: 1.3708x; 1.1166x over previous
//
#include <hip/hip_runtime.h>
#include <math.h>

#define PAD_IDX 0
#define BIGV 10000.0f
constexpr int B_ = 1024, S_ = 128, V_ = 200, E_ = 512, H_ = 512, T_ = 24;

// ws layout (float offsets):
//   w1T    [512][512]  @ 0        (w1 transposed: w1T[k][t] = w1[t][k])
//   h_ws   [200][512]  @ 262144
//   em_tab [200][24]   @ 364544
//   w_tab  [200][24]   @ 369344
//   emax   [200]       @ 374144
constexpr int OFF_H  = 262144;
constexpr int OFF_EM = 364544;
constexpr int OFF_W  = 369344;
constexpr int OFF_MX = 374144;

// ---------------------------------------------------------------------------
// Kernel T: transpose w1 (512x512) via 64x64 LDS tiles (+1 pad, conflict-free).
// Both load and store coalesced. Also zero-inits out[0] for crf's atomics.
// R4 post-mortem: per-thread row walks put 64 distinct cache lines behind every
// load inst (TA-bound, 42us). Transposing once makes the GEMM reads coalesced.
// ---------------------------------------------------------------------------
__global__ __launch_bounds__(256) void transpose_kernel(
    const float* __restrict__ w1, float* __restrict__ w1T,
    float* __restrict__ out)
{
    __shared__ float tile[64][65];
    const int bi = blockIdx.x >> 3, bj = blockIdx.x & 7;
    const int tx = threadIdx.x & 63, r0 = (threadIdx.x >> 6) * 16;
    if (blockIdx.x == 0 && threadIdx.x == 0) out[0] = 0.f;
    #pragma unroll
    for (int m = 0; m < 16; ++m) {
        const int r = r0 + m;
        tile[r][tx] = w1[(size_t)(bi * 64 + r) * 512 + bj * 64 + tx];
    }
    __syncthreads();
    #pragma unroll
    for (int m = 0; m < 16; ++m) {
        const int r = r0 + m;
        w1T[(size_t)(bj * 64 + r) * 512 + bi * 64 + tx] = tile[tx][r];
    }
}

// ---------------------------------------------------------------------------
// Kernel A1: h_ws[v][t] = relu(emb[v] . w1[t] + b1[t]) for a v-pair.
// Grid: 100 v-pairs x 2 row-halves = 200 blocks. Thread = one row t, two v.
// w1T[k][t]: consecutive lanes -> consecutive addresses (coalesced b32).
// emb[v][k]: wave-uniform address -> scalar-cache load, off the VMEM pipe.
// v-pair tiling halves L2 w-traffic (100 MB total ~ 3 us L2 floor).
// 4 independent FMA chains per thread; unroll 8 keeps 16 loads in flight.
// ---------------------------------------------------------------------------
__global__ __launch_bounds__(256) void h_kernel(
    const float* __restrict__ emb, const float* __restrict__ w1T,
    const float* __restrict__ b1, float* __restrict__ h_ws)
{
    const int pair = blockIdx.x >> 1;
    const int half = blockIdx.x & 1;
    const int v0 = pair * 2, v1 = v0 + 1;
    const int t = half * 256 + threadIdx.x;
    const float* __restrict__ x0 = emb + (size_t)v0 * E_;
    const float* __restrict__ x1 = emb + (size_t)v1 * E_;

    float a00 = 0.f, a01 = 0.f, a10 = 0.f, a11 = 0.f;
    #pragma unroll 8
    for (int k = 0; k < E_; k += 2) {
        const float wv0 = w1T[(size_t)k * H_ + t];
        const float wv1 = w1T[(size_t)(k + 1) * H_ + t];
        a00 = fmaf(wv0, x0[k],     a00);
        a10 = fmaf(wv0, x1[k],     a10);
        a01 = fmaf(wv1, x0[k + 1], a01);
        a11 = fmaf(wv1, x1[k + 1], a11);
    }
    const float bb = b1[t];
    h_ws[(size_t)v0 * H_ + t] = fmaxf((a00 + a01) + bb, 0.f);
    h_ws[(size_t)v1 * H_ + t] = fmaxf((a10 + a11) + bb, 0.f);
}

// ---------------------------------------------------------------------------
// Kernel A2: em_table[v][t] = relu(h[v] . w2[t] + b2[t]) (+BIG at [0][0]),
// emax[v] = row max, w_table[v][t] = exp(em - emax).
// One block per v; 4 waves x 6 outputs, split-K-64 + shfl reduce (proven R4
// phase-2/3 structure; h and w2 reads are lane-coalesced).
// ---------------------------------------------------------------------------
__global__ __launch_bounds__(256) void emis_kernel(
    const float* __restrict__ h_ws, const float* __restrict__ w2,
    const float* __restrict__ b2, float* __restrict__ em_table,
    float* __restrict__ w_table, float* __restrict__ emax_arr)
{
    __shared__ float em_row[32];
    const int v = blockIdx.x;
    const int t = threadIdx.x;
    const int wave = t >> 6, lane = t & 63;
    const float* __restrict__ hrow = h_ws + (size_t)v * H_;

    for (int jj2 = 0; jj2 < 6; ++jj2) {
        const int jo = wave * 6 + jj2;
        float part = 0.f;
        #pragma unroll
        for (int m = 0; m < H_ / 64; ++m) {
            const int k = lane + m * 64;
            part = fmaf(hrow[k], w2[(size_t)jo * H_ + k], part);
        }
        #pragma unroll
        for (int off = 32; off; off >>= 1)
            part += __shfl_xor(part, off, 64);
        if (lane == 0) {
            float val = fmaxf(part + b2[jo], 0.f);
            if (v == 0 && jo == PAD_IDX) val += BIGV;  // pad boost baked in
            em_row[jo] = val;
        }
    }
    __syncthreads();

    if (t < 32) {
        float x = (t < T_) ? em_row[t] : -INFINITY;
        float mx = x;
        #pragma unroll
        for (int off = 16; off; off >>= 1)
            mx = fmaxf(mx, __shfl_xor(mx, off, 32));
        if (t < T_) {
            em_table[v * T_ + t] = x;
            w_table[v * T_ + t]  = __expf(x - mx);
        }
        if (t == 0) emax_arr[v] = mx;
    }
}

// ---------------------------------------------------------------------------
// Kernel B: CRF forward in probability domain (unchanged math, absmax was 0.0).
// Occupancy fix vs R4: 4 batches/block x 256 blocks -> all 256 CUs carry the
// DS swizzle load (was 128 blocks = half the CUs idle). em_s staging dropped;
// gold path reads em_table via L2 (one-time scattered reads).
// Fused finale: atomicAdd of (denom - gold)/B into out[0].
// ---------------------------------------------------------------------------
#define ACC4(base)                                                              \
    s0 = fmaf(__uint_as_float(__builtin_amdgcn_ds_swizzle(qi, (base) << 5)),     \
              Ecol[(base)], s0);                                                \
    s1 = fmaf(__uint_as_float(__builtin_amdgcn_ds_swizzle(qi, ((base)+1) << 5)), \
              Ecol[(base)+1], s1);                                              \
    s2 = fmaf(__uint_as_float(__builtin_amdgcn_ds_swizzle(qi, ((base)+2) << 5)), \
              Ecol[(base)+2], s2);                                              \
    s3 = fmaf(__uint_as_float(__builtin_amdgcn_ds_swizzle(qi, ((base)+3) << 5)), \
              Ecol[(base)+3], s3);

__global__ __launch_bounds__(128) void crf_kernel(
    const int* __restrict__ seq, const int* __restrict__ labels,
    const float* __restrict__ start_t, const float* __restrict__ end_t,
    const float* __restrict__ trans, const float* __restrict__ em_table,
    const float* __restrict__ w_table, const float* __restrict__ emax_arr,
    float* __restrict__ out)
{
    __shared__ __align__(16) float w_s[V_ * T_];
    __shared__ float emax_s[V_];
    __shared__ int   tok_s[4 * S_];
    const int tid = threadIdx.x;
    {
        const float4* __restrict__ src = (const float4*)w_table;
        float4* dst = (float4*)w_s;
        for (int i = tid; i < V_ * T_ / 4; i += 128) dst[i] = src[i];
    }
    for (int i = tid; i < V_; i += 128) emax_s[i] = emax_arr[i];
    {
        const int base = blockIdx.x * 4 * S_;
        #pragma unroll
        for (int i = 0; i < 4; ++i)
            tok_s[tid + i * 128] = seq[base + tid + i * 128];
    }
    __syncthreads();

    const int grp = tid >> 5, j = tid & 31;
    const int b = blockIdx.x * 4 + grp;
    const int jj = (j < T_) ? j : 0;
    const bool act = (j < T_);
    const int* __restrict__ lrow = labels + (size_t)b * S_;
    const int* __restrict__ tks  = tok_s + grp * S_;

    float Ecol[T_];
    #pragma unroll
    for (int i = 0; i < T_; ++i)
        Ecol[i] = __expf(trans[i * T_ + jj]);

    // init: alpha0 in log domain, one exp into prob domain
    const int tok0 = tks[0];
    const float a0 = start_t[jj] + em_table[tok0 * T_ + jj];
    float m0 = a0;
    #pragma unroll
    for (int off = 16; off; off >>= 1)
        m0 = fmaxf(m0, __shfl_xor(m0, off, 32));
    float q = __expf(a0 - m0);   // inactive lanes mirror state 0: harmless
    float logacc = m0;

    // software pipeline: wv = w row for step s; tokB = token for step s+1
    float wv; int tokB;
    { const int tA = tks[1]; wv = w_s[tA * T_ + jj]; tokB = tks[2]; }

    for (int s = 1; s < S_; ++s) {
        const float wn = w_s[tokB * T_ + jj];            // emit weights, step s+1
        const int tokC = tks[(s + 2 < S_) ? s + 2 : S_ - 1];
        const unsigned qi = __float_as_uint(q);
        float s0 = 0.f, s1 = 0.f, s2 = 0.f, s3 = 0.f;
        ACC4(0) ACC4(4) ACC4(8) ACC4(12) ACC4(16) ACC4(20)
        q = ((s0 + s1) + (s2 + s3)) * wv;
        wv = wn; tokB = tokC;
        if ((s & 15) == 0) {                              // renorm every 16 steps
            float m = q;
            #pragma unroll
            for (int off = 16; off; off >>= 1)
                m = fmaxf(m, __shfl_xor(m, off, 32));
            q *= (1.0f / m);
            logacc += __logf(m);
        }
    }

    // denominator tail: log sum q_j * exp(end_j)
    float fin = act ? q * __expf(end_t[jj]) : 0.f;
    #pragma unroll
    for (int off = 16; off; off >>= 1)
        fin += __shfl_xor(fin, off, 32);
    const float denom_part = logacc + __logf(fin);  // missing Sum emax, folded below

    // gold path score minus Sum_{s>=1} emax[tok_s]
    float gp = 0.f;
    #pragma unroll
    for (int r = 0; r < 4; ++r) {
        const int s = j + r * 32;
        const int tk = tks[s];
        const int ls = lrow[s];
        gp += em_table[tk * T_ + ls];
        if (s >= 1) gp -= emax_s[tk];
        if (s < S_ - 1) gp += trans[ls * T_ + lrow[s + 1]];
        if (s == 0) gp += start_t[ls];
        if (s == S_ - 1) gp += end_t[ls];
    }
    #pragma unroll
    for (int off = 16; off; off >>= 1)
        gp += __shfl_xor(gp, off, 32);

    // fused mean: out = mean_b(denom_b - gold_b) = -mean(llh)
    if (j == 0)
        atomicAdd(out, (denom_part - gp) * (1.0f / (float)B_));
}

// ---------------------------------------------------------------------------
extern "C" void kernel_launch(void* const* d_in, const int* in_sizes, int n_in,
                              void* d_out, int out_size, void* d_ws, size_t ws_size,
                              hipStream_t stream) {
    const int*   seq     = (const int*)d_in[0];
    const int*   labels  = (const int*)d_in[1];
    // d_in[2] true_lengths: unused by the reference forward
    const float* emb     = (const float*)d_in[3];
    const float* w1      = (const float*)d_in[4];
    const float* b1      = (const float*)d_in[5];
    const float* w2      = (const float*)d_in[6];
    const float* b2      = (const float*)d_in[7];
    const float* start_t = (const float*)d_in[8];
    const float* end_t   = (const float*)d_in[9];
    const float* trans   = (const float*)d_in[10];

    float* ws       = (float*)d_ws;
    float* w1T      = ws;
    float* h_ws     = ws + OFF_H;
    float* em_table = ws + OFF_EM;
    float* w_table  = ws + OFF_W;
    float* emax_arr = ws + OFF_MX;
    float* out      = (float*)d_out;

    transpose_kernel<<<64, 256, 0, stream>>>(w1, w1T, out);
    h_kernel<<<200, 256, 0, stream>>>(emb, w1T, b1, h_ws);
    emis_kernel<<<V_, 256, 0, stream>>>(h_ws, w2, b2, em_table, w_table, emax_arr);
    crf_kernel<<<B_ / 4, 128, 0, stream>>>(seq, labels, start_t, end_t, trans,
                                           em_table, w_table, emax_arr, out);
}

// Round 6
// 120.041 us; speedup vs baseline: 1.4556x; 1.0619x over previous
//
#include <hip/hip_runtime.h>
#include <math.h>

#define PAD_IDX 0
#define BIGV 10000.0f
constexpr int B_ = 1024, S_ = 128, V_ = 200, E_ = 512, H_ = 512, T_ = 24;

// ws layout (float offsets):
//   w1T    [512][512]  @ 0        (w1 transposed: w1T[k][t] = w1[t][k])
//   h_ws   [200][512]  @ 262144
//   em_tab [200][24]   @ 364544
//   w_tab  [200][24]   @ 369344
//   emax   [200]       @ 374144
constexpr int OFF_H  = 262144;
constexpr int OFF_EM = 364544;
constexpr int OFF_W  = 369344;
constexpr int OFF_MX = 374144;

// ---------------------------------------------------------------------------
// Kernel T: transpose w1 (512x512) via 64x64 LDS tiles (+1 pad, conflict-free).
// Both load and store coalesced. Also zero-inits out[0] for crf's atomics.
// ---------------------------------------------------------------------------
__global__ __launch_bounds__(256) void transpose_kernel(
    const float* __restrict__ w1, float* __restrict__ w1T,
    float* __restrict__ out)
{
    __shared__ float tile[64][65];
    const int bi = blockIdx.x >> 3, bj = blockIdx.x & 7;
    const int tx = threadIdx.x & 63, r0 = (threadIdx.x >> 6) * 16;
    if (blockIdx.x == 0 && threadIdx.x == 0) out[0] = 0.f;
    #pragma unroll
    for (int m = 0; m < 16; ++m) {
        const int r = r0 + m;
        tile[r][tx] = w1[(size_t)(bi * 64 + r) * 512 + bj * 64 + tx];
    }
    __syncthreads();
    #pragma unroll
    for (int m = 0; m < 16; ++m) {
        const int r = r0 + m;
        w1T[(size_t)(bj * 64 + r) * 512 + bi * 64 + tx] = tile[tx][r];
    }
}

// ---------------------------------------------------------------------------
// Kernel A1: h_ws[v][t] = relu(emb[v].w1[t] + b1[t]) for a v-pair, t-half.
// R5 post-mortem: old version ran ~24us (fixed-overhead model) — 1024 b32
// VMEM instrs/thread with un-scalarized broadcast x-loads in the dependence
// stream. This version: thread (part,quad) = t-quad [quad*4..+3], k-range
// [part*128..+128). Per iter: 1 coalesced dwordx4 w-load (1024B/wave) +
// 1 ds_read_b64 (interleaved x-pair, wave-uniform broadcast) + 8 indep FMA
// chains. 8x fewer VMEM instrs, 4x k-parallelism. Partials via 8KB LDS.
// ---------------------------------------------------------------------------
__global__ __launch_bounds__(256) void h_kernel(
    const float* __restrict__ emb, const float* __restrict__ w1T,
    const float* __restrict__ b1, float* __restrict__ h_ws)
{
    __shared__ float xi[2 * E_];           // interleaved {x0[k], x1[k]}
    __shared__ float part_s[4][64][8];     // [k-part][t-quad][4t x 2v]
    const int pair = blockIdx.x >> 1, half = blockIdx.x & 1;
    const int v0 = pair * 2, v1 = v0 + 1;
    const int tid = threadIdx.x;

    // stage x interleaved: xi[2k]=emb[v0][k], xi[2k+1]=emb[v1][k]
    {
        const float* __restrict__ x0 = emb + (size_t)v0 * E_;
        const float* __restrict__ x1 = emb + (size_t)v1 * E_;
        #pragma unroll
        for (int m = 0; m < 2; ++m) {
            const int k = tid + m * 256;
            xi[2 * k]     = x0[k];
            xi[2 * k + 1] = x1[k];
        }
    }
    __syncthreads();

    const int part = tid >> 6;             // 0..3  (k partition)
    const int quad = tid & 63;             // 0..63 (t quad)
    const int t0 = half * 256 + quad * 4;
    const int k0 = part * 128;

    float a0 = 0.f, a1 = 0.f, a2 = 0.f, a3 = 0.f;
    float c0 = 0.f, c1 = 0.f, c2 = 0.f, c3 = 0.f;
    const float4* __restrict__ wp = (const float4*)(w1T + (size_t)k0 * H_ + t0);
    const float2* __restrict__ xp = (const float2*)xi + k0;
    #pragma unroll 4
    for (int i = 0; i < 128; ++i) {
        const float4 w = wp[(size_t)i * (H_ / 4)];
        const float2 x = xp[i];
        a0 = fmaf(w.x, x.x, a0); a1 = fmaf(w.y, x.x, a1);
        a2 = fmaf(w.z, x.x, a2); a3 = fmaf(w.w, x.x, a3);
        c0 = fmaf(w.x, x.y, c0); c1 = fmaf(w.y, x.y, c1);
        c2 = fmaf(w.z, x.y, c2); c3 = fmaf(w.w, x.y, c3);
    }
    part_s[part][quad][0] = a0; part_s[part][quad][1] = a1;
    part_s[part][quad][2] = a2; part_s[part][quad][3] = a3;
    part_s[part][quad][4] = c0; part_s[part][quad][5] = c1;
    part_s[part][quad][6] = c2; part_s[part][quad][7] = c3;
    __syncthreads();

    // combine 4 k-partials; thread tid -> local t = tid, both v's
    {
        const int q2 = tid >> 2, r0 = tid & 3;
        const float s0 = (part_s[0][q2][r0]     + part_s[1][q2][r0])
                       + (part_s[2][q2][r0]     + part_s[3][q2][r0]);
        const float s1 = (part_s[0][q2][r0 + 4] + part_s[1][q2][r0 + 4])
                       + (part_s[2][q2][r0 + 4] + part_s[3][q2][r0 + 4]);
        const int t = half * 256 + tid;
        const float bb = b1[t];
        h_ws[(size_t)v0 * H_ + t] = fmaxf(s0 + bb, 0.f);
        h_ws[(size_t)v1 * H_ + t] = fmaxf(s1 + bb, 0.f);
    }
}

// ---------------------------------------------------------------------------
// Kernel A2: em_table[v][t] = relu(h[v].w2[t] + b2[t]) (+BIG at [0][0]),
// emax[v] = row max, w_table[v][t] = exp(em - emax).
// ---------------------------------------------------------------------------
__global__ __launch_bounds__(256) void emis_kernel(
    const float* __restrict__ h_ws, const float* __restrict__ w2,
    const float* __restrict__ b2, float* __restrict__ em_table,
    float* __restrict__ w_table, float* __restrict__ emax_arr)
{
    __shared__ float em_row[32];
    const int v = blockIdx.x;
    const int t = threadIdx.x;
    const int wave = t >> 6, lane = t & 63;
    const float* __restrict__ hrow = h_ws + (size_t)v * H_;

    for (int jj2 = 0; jj2 < 6; ++jj2) {
        const int jo = wave * 6 + jj2;
        float part = 0.f;
        #pragma unroll
        for (int m = 0; m < H_ / 64; ++m) {
            const int k = lane + m * 64;
            part = fmaf(hrow[k], w2[(size_t)jo * H_ + k], part);
        }
        #pragma unroll
        for (int off = 32; off; off >>= 1)
            part += __shfl_xor(part, off, 64);
        if (lane == 0) {
            float val = fmaxf(part + b2[jo], 0.f);
            if (v == 0 && jo == PAD_IDX) val += BIGV;  // pad boost baked in
            em_row[jo] = val;
        }
    }
    __syncthreads();

    if (t < 32) {
        float x = (t < T_) ? em_row[t] : -INFINITY;
        float mx = x;
        #pragma unroll
        for (int off = 16; off; off >>= 1)
            mx = fmaxf(mx, __shfl_xor(mx, off, 32));
        if (t < T_) {
            em_table[v * T_ + t] = x;
            w_table[v * T_ + t]  = __expf(x - mx);
        }
        if (t == 0) emax_arr[v] = mx;
    }
}

// ---------------------------------------------------------------------------
// Kernel B: CRF forward in probability domain (unchanged from R5: absmax 0.0,
// est ~12us; 4 batches/block x 256 blocks spreads DS load over all CUs).
// ---------------------------------------------------------------------------
#define ACC4(base)                                                              \
    s0 = fmaf(__uint_as_float(__builtin_amdgcn_ds_swizzle(qi, (base) << 5)),     \
              Ecol[(base)], s0);                                                \
    s1 = fmaf(__uint_as_float(__builtin_amdgcn_ds_swizzle(qi, ((base)+1) << 5)), \
              Ecol[(base)+1], s1);                                              \
    s2 = fmaf(__uint_as_float(__builtin_amdgcn_ds_swizzle(qi, ((base)+2) << 5)), \
              Ecol[(base)+2], s2);                                              \
    s3 = fmaf(__uint_as_float(__builtin_amdgcn_ds_swizzle(qi, ((base)+3) << 5)), \
              Ecol[(base)+3], s3);

__global__ __launch_bounds__(128) void crf_kernel(
    const int* __restrict__ seq, const int* __restrict__ labels,
    const float* __restrict__ start_t, const float* __restrict__ end_t,
    const float* __restrict__ trans, const float* __restrict__ em_table,
    const float* __restrict__ w_table, const float* __restrict__ emax_arr,
    float* __restrict__ out)
{
    __shared__ __align__(16) float w_s[V_ * T_];
    __shared__ float emax_s[V_];
    __shared__ int   tok_s[4 * S_];
    const int tid = threadIdx.x;
    {
        const float4* __restrict__ src = (const float4*)w_table;
        float4* dst = (float4*)w_s;
        for (int i = tid; i < V_ * T_ / 4; i += 128) dst[i] = src[i];
    }
    for (int i = tid; i < V_; i += 128) emax_s[i] = emax_arr[i];
    {
        const int base = blockIdx.x * 4 * S_;
        #pragma unroll
        for (int i = 0; i < 4; ++i)
            tok_s[tid + i * 128] = seq[base + tid + i * 128];
    }
    __syncthreads();

    const int grp = tid >> 5, j = tid & 31;
    const int b = blockIdx.x * 4 + grp;
    const int jj = (j < T_) ? j : 0;
    const bool act = (j < T_);
    const int* __restrict__ lrow = labels + (size_t)b * S_;
    const int* __restrict__ tks  = tok_s + grp * S_;

    float Ecol[T_];
    #pragma unroll
    for (int i = 0; i < T_; ++i)
        Ecol[i] = __expf(trans[i * T_ + jj]);

    // init: alpha0 in log domain, one exp into prob domain
    const int tok0 = tks[0];
    const float a0 = start_t[jj] + em_table[tok0 * T_ + jj];
    float m0 = a0;
    #pragma unroll
    for (int off = 16; off; off >>= 1)
        m0 = fmaxf(m0, __shfl_xor(m0, off, 32));
    float q = __expf(a0 - m0);   // inactive lanes mirror state 0: harmless
    float logacc = m0;

    // software pipeline: wv = w row for step s; tokB = token for step s+1
    float wv; int tokB;
    { const int tA = tks[1]; wv = w_s[tA * T_ + jj]; tokB = tks[2]; }

    for (int s = 1; s < S_; ++s) {
        const float wn = w_s[tokB * T_ + jj];            // emit weights, step s+1
        const int tokC = tks[(s + 2 < S_) ? s + 2 : S_ - 1];
        const unsigned qi = __float_as_uint(q);
        float s0 = 0.f, s1 = 0.f, s2 = 0.f, s3 = 0.f;
        ACC4(0) ACC4(4) ACC4(8) ACC4(12) ACC4(16) ACC4(20)
        q = ((s0 + s1) + (s2 + s3)) * wv;
        wv = wn; tokB = tokC;
        if ((s & 15) == 0) {                              // renorm every 16 steps
            float m = q;
            #pragma unroll
            for (int off = 16; off; off >>= 1)
                m = fmaxf(m, __shfl_xor(m, off, 32));
            q *= (1.0f / m);
            logacc += __logf(m);
        }
    }

    // denominator tail: log sum q_j * exp(end_j)
    float fin = act ? q * __expf(end_t[jj]) : 0.f;
    #pragma unroll
    for (int off = 16; off; off >>= 1)
        fin += __shfl_xor(fin, off, 32);
    const float denom_part = logacc + __logf(fin);  // missing Sum emax, folded below

    // gold path score minus Sum_{s>=1} emax[tok_s]
    float gp = 0.f;
    #pragma unroll
    for (int r = 0; r < 4; ++r) {
        const int s = j + r * 32;
        const int tk = tks[s];
        const int ls = lrow[s];
        gp += em_table[tk * T_ + ls];
        if (s >= 1) gp -= emax_s[tk];
        if (s < S_ - 1) gp += trans[ls * T_ + lrow[s + 1]];
        if (s == 0) gp += start_t[ls];
        if (s == S_ - 1) gp += end_t[ls];
    }
    #pragma unroll
    for (int off = 16; off; off >>= 1)
        gp += __shfl_xor(gp, off, 32);

    // fused mean: out = mean_b(denom_b - gold_b) = -mean(llh)
    if (j == 0)
        atomicAdd(out, (denom_part - gp) * (1.0f / (float)B_));
}

// ---------------------------------------------------------------------------
extern "C" void kernel_launch(void* const* d_in, const int* in_sizes, int n_in,
                              void* d_out, int out_size, void* d_ws, size_t ws_size,
                              hipStream_t stream) {
    const int*   seq     = (const int*)d_in[0];
    const int*   labels  = (const int*)d_in[1];
    // d_in[2] true_lengths: unused by the reference forward
    const float* emb     = (const float*)d_in[3];
    const float* w1      = (const float*)d_in[4];
    const float* b1      = (const float*)d_in[5];
    const float* w2      = (const float*)d_in[6];
    const float* b2      = (const float*)d_in[7];
    const float* start_t = (const float*)d_in[8];
    const float* end_t   = (const float*)d_in[9];
    const float* trans   = (const float*)d_in[10];

    float* ws       = (float*)d_ws;
    float* w1T      = ws;
    float* h_ws     = ws + OFF_H;
    float* em_table = ws + OFF_EM;
    float* w_table  = ws + OFF_W;
    float* emax_arr = ws + OFF_MX;
    float* out      = (float*)d_out;

    transpose_kernel<<<64, 256, 0, stream>>>(w1, w1T, out);
    h_kernel<<<200, 256, 0, stream>>>(emb, w1T, b1, h_ws);
    emis_kernel<<<V_, 256, 0, stream>>>(h_ws, w2, b2, em_table, w_table, emax_arr);
    crf_kernel<<<B_ / 4, 128, 0, stream>>>(seq, labels, start_t, end_t, trans,
                                           em_table, w_table, emax_arr, out);
}